// Round 1
// baseline (1197.772 us; speedup 1.0000x reference)
//
#include <hip/hip_runtime.h>

typedef unsigned int uint32;

#define HW 9216
#define NBATCH 512
#define NPAIR 1024
#define NITER 100
#define TWO_PI_F 6.28318530717958647692f

// ---------------- helpers ----------------

__device__ __forceinline__ float block_reduce_sum(float v, float* lds) {
  // call from all threads; result valid on thread 0. lds must hold >= blockDim/64 floats
#pragma unroll
  for (int m = 1; m < 64; m <<= 1) v += __shfl_xor(v, m, 64);
  __syncthreads();  // guard lds reuse across consecutive calls
  if ((threadIdx.x & 63) == 0) lds[threadIdx.x >> 6] = v;
  __syncthreads();
  if (threadIdx.x == 0) {
    int nw = blockDim.x >> 6;
    for (int w = 1; w < nw; ++w) v += lds[w];
  }
  return v;
}

// ---------------- init ----------------

__global__ void init_kernel(double* acc) {
  if (threadIdx.x < 2) acc[threadIdx.x] = 0.0;
}

// ---------------- per-sample totals (sum of image) ----------------

__global__ void totals_kernel(const float* __restrict__ yt, const float* __restrict__ yp,
                              float* __restrict__ totals) {
  __shared__ float lds[4];
  int pair = blockIdx.x;
  const float* img = (pair < NBATCH) ? (yt + (size_t)pair * HW)
                                     : (yp + (size_t)(pair - NBATCH) * HW);
  float s = 0.f;
  for (int j = threadIdx.x; j < HW; j += 256) s += img[j];
  s = block_reduce_sum(s, lds);
  if (threadIdx.x == 0) totals[pair] = s;
}

// ---------------- exact percentile via radix select ----------------

__device__ float radix_select(const float* __restrict__ img, int rank,
                              uint32* bins, uint32* selb) {
  uint32 prefix = 0;
  int r = rank;
#pragma unroll 1
  for (int pass = 0; pass < 4; ++pass) {
    int shift = 24 - 8 * pass;
    uint32 maskhi = (pass == 0) ? 0u : (0xFFFFFFFFu << (shift + 8));
    bins[threadIdx.x] = 0;
    __syncthreads();
    for (int j = 0; j < 36; ++j) {
      int px = threadIdx.x + j * 256;
      uint32 bits = __float_as_uint(img[px]);
      uint32 key = (bits & 0x80000000u) ? ~bits : (bits | 0x80000000u);
      if ((key & maskhi) == prefix)
        atomicAdd(&bins[(key >> shift) & 255u], 1u);
    }
    __syncthreads();
    uint32 c = bins[threadIdx.x];
    // inclusive scan (Hillis-Steele)
    for (int d = 1; d < 256; d <<= 1) {
      uint32 v = (threadIdx.x >= (unsigned)d) ? bins[threadIdx.x - d] : 0u;
      __syncthreads();
      bins[threadIdx.x] += v;
      __syncthreads();
    }
    uint32 inc = bins[threadIdx.x];
    if (inc > (uint32)r && (inc - c) <= (uint32)r) {
      selb[0] = threadIdx.x;
      selb[1] = (uint32)r - (inc - c);
    }
    __syncthreads();
    prefix |= (selb[0] << shift);
    r = (int)selb[1];
    __syncthreads();
  }
  uint32 key = prefix;
  uint32 bits = (key & 0x80000000u) ? (key ^ 0x80000000u) : ~key;
  return __uint_as_float(bits);
}

__global__ void percentile_kernel(const float* __restrict__ blurred,
                                  float* __restrict__ vmin, float* __restrict__ vmax) {
  __shared__ uint32 bins[256];
  __shared__ uint32 selb[2];
  int b = blockIdx.x;
  const float* img = blurred + (size_t)b * HW;
  float lo = radix_select(img, 92, bins, selb);     // round(0.01*9215) = 92
  float hi = radix_select(img, 9123, bins, selb);   // round(0.99*9215) = 9123
  if (threadIdx.x == 0) { vmin[b] = lo; vmax[b] = hi; }
}

// ---------------- weighted MSE ----------------

__global__ void wmse_kernel(const float4* __restrict__ yt, const float4* __restrict__ yp,
                            const float4* __restrict__ wm, double* acc) {
  __shared__ float lds[4];
  int idx = blockIdx.x * 256 + threadIdx.x;
  int stride = gridDim.x * 256;
  float s = 0.f;
  for (int i = idx; i < (NBATCH * HW / 4); i += stride) {
    float4 a = yp[i], b = yt[i], w = wm[i];
    float d;
    d = a.x - b.x; s = fmaf(d * d, w.x, s);
    d = a.y - b.y; s = fmaf(d * d, w.y, s);
    d = a.z - b.z; s = fmaf(d * d, w.z, s);
    d = a.w - b.w; s = fmaf(d * d, w.w, s);
  }
  s = block_reduce_sum(s, lds);
  if (threadIdx.x == 0) atomicAdd(&acc[0], (double)s);
}

// ---------------- depthwise 25x25 SAME conv + reblur loss ----------------

__device__ __forceinline__ void accum_row(float* a, const float fr[28], const float* krow) {
  float kv[28];
#pragma unroll
  for (int q = 0; q < 7; ++q) {
    float4 t = *reinterpret_cast<const float4*>(krow + 4 * q);
    kv[4 * q + 0] = t.x; kv[4 * q + 1] = t.y; kv[4 * q + 2] = t.z; kv[4 * q + 3] = t.w;
  }
#pragma unroll
  for (int dx = 0; dx < 25; ++dx) {
    a[0] = fmaf(fr[dx + 0], kv[dx], a[0]);
    a[1] = fmaf(fr[dx + 1], kv[dx], a[1]);
    a[2] = fmaf(fr[dx + 2], kv[dx], a[2]);
    a[3] = fmaf(fr[dx + 3], kv[dx], a[3]);
  }
}

__global__ __launch_bounds__(256, 2) void conv_kernel(
    const float* __restrict__ yp, const float* __restrict__ ker,
    const float* __restrict__ blurred, const float* __restrict__ wmap,
    const float* __restrict__ vminA, const float* __restrict__ vmaxA,
    double* acc) {
  __shared__ float pad[120 * 120];
  __shared__ float kr[25 * 28];
  __shared__ float lds[4];
  __shared__ float sInv;
  int b = blockIdx.x, tid = threadIdx.x;

  // stage kernel (rows padded to 28, zero-filled) + sum
  const float* kg = ker + (size_t)b * 625;
  float ks = 0.f;
  for (int i = tid; i < 700; i += 256) {
    int r = i / 28, c = i - r * 28;
    float v = (c < 25) ? kg[r * 25 + c] : 0.f;
    kr[i] = v;
    ks += v;
  }
  float ksum = block_reduce_sum(ks, lds);
  if (tid == 0) sInv = 1.f / (ksum + 1e-6f);

  // stage zero-padded image (pad 12 each side)
  const float* ig = yp + (size_t)b * HW;
  for (int i = tid; i < 14400; i += 256) {
    int r = i / 120, c = i - r * 120;
    float v = 0.f;
    if (r >= 12 && r < 108 && c >= 12 && c < 108) v = ig[(r - 12) * 96 + (c - 12)];
    pad[i] = v;
  }
  __syncthreads();

  float inv = sInv;
  float vmn = vminA[b], vmx = vmaxA[b];
  float scale = vmx - vmn + 1e-6f;
  const float* bl = blurred + (size_t)b * HW;
  const float* wm = wmap + (size_t)b * HW;

  float part = 0.f;
#pragma unroll 1
  for (int t3 = 0; t3 < 3; ++t3) {
    int tile = tid + t3 * 256;          // 0..767
    int ty = tile / 24, tx = tile - ty * 24;
    int y0 = ty * 3, x0 = tx * 4;
    float a0[4] = {0, 0, 0, 0}, a1[4] = {0, 0, 0, 0}, a2[4] = {0, 0, 0, 0};
#pragma unroll 1
    for (int ir = 0; ir < 27; ++ir) {
      float fr[28];
      const float* rp = &pad[(y0 + ir) * 120 + x0];
#pragma unroll
      for (int q = 0; q < 7; ++q) {
        float4 t = *reinterpret_cast<const float4*>(rp + 4 * q);
        fr[4 * q + 0] = t.x; fr[4 * q + 1] = t.y; fr[4 * q + 2] = t.z; fr[4 * q + 3] = t.w;
      }
      if (ir <= 24)            accum_row(a0, fr, &kr[ir * 28]);
      if (ir >= 1 && ir <= 25) accum_row(a1, fr, &kr[(ir - 1) * 28]);
      if (ir >= 2)             accum_row(a2, fr, &kr[(ir - 2) * 28]);
    }
    // epilogue: normalize, clip-rescale, accumulate reblur loss
    {
      const float* aa = a0;
#pragma unroll
      for (int r = 0; r < 3; ++r) {
        aa = (r == 0) ? a0 : ((r == 1) ? a1 : a2);
#pragma unroll
        for (int j = 0; j < 4; ++j) {
          int px = (y0 + r) * 96 + x0 + j;
          float raw = aa[j] * inv;
          float rb2 = fminf(fmaxf((raw - vmn) / scale, 0.f), 2.f);
          float d = rb2 - bl[px];
          part = fmaf(d * d, wm[px], part);
        }
      }
    }
  }
  part = block_reduce_sum(part, lds);
  if (tid == 0) atomicAdd(&acc[1], (double)part);
}

// ---------------- ellipticity: full trajectories (kernel A) ----------------

__global__ __launch_bounds__(256, 4) void ellipA_kernel(
    const float* __restrict__ yt, const float* __restrict__ yp,
    const float* __restrict__ totals,
    float* __restrict__ dxx, float* __restrict__ dyy,
    float* __restrict__ e1a, float* __restrict__ e2a) {
  const int pair = blockIdx.x;
  const int tid = threadIdx.x;
  const float* img = (pair < NBATCH) ? (yt + (size_t)pair * HW)
                                     : (yp + (size_t)(pair - NBATCH) * HW);
  float im[36];
#pragma unroll
  for (int j = 0; j < 36; ++j) im[j] = img[tid + j * 256];

  __shared__ float bc[8];     // mux,muy,back,A,c1,c2,c3
  __shared__ float rbuf[28];  // 4 waves x 7 partials
  __shared__ int sfroz;

  // state lives on thread 0
  float ax = 3.f, ay = 3.f, axy = 0.f, mux = 0.f, muy = 0.f, back = 0.f;
  float psxx = 0.f, psyy = 0.f;
  float total = 0.f;
  if (tid == 0) {
    total = totals[pair];
    sfroz = 0;
    float rho = fminf(fmaxf(axy / (ax * ay + 1e-10f), -0.99f), 0.99f);
    float arb = fmaxf(2.f * (1.f - rho * rho), 1e-10f);
    float Ac = 1.f / (TWO_PI_F * ax * ay * sqrtf(1.f - rho * rho));
    bc[0] = mux; bc[1] = muy; bc[2] = back; bc[3] = Ac;
    bc[4] = 1.f / (arb * ax * ax);
    bc[5] = 1.f / (arb * ay * ay);
    bc[6] = -2.f * axy / (arb * ax * ax * ay * ay);
  }
  __syncthreads();

#pragma unroll 1
  for (int n = 0; n < NITER; ++n) {
    float bmux = bc[0], bmuy = bc[1], bback = bc[2], Ac = bc[3];
    float c1 = bc[4], c2 = bc[5], c3 = bc[6];
    float s0 = 0, sx = 0, sy = 0, sxx = 0, syy = 0, sxy = 0, s7 = 0;
    int x = tid % 96, y = tid / 96;  // px = tid + 256*j
#pragma unroll
    for (int j = 0; j < 36; ++j) {
      float Xc = ((float)x - 47.5f) - bmux;
      float Yc = ((float)y - 47.5f) - bmuy;
      float xc2 = Xc * Xc, yc2 = Yc * Yc, xy = Xc * Yc;
      float t = fmaf(c1, xc2, fmaf(c2, yc2, c3 * xy));
      t = fminf(fmaxf(t, 0.f), 50.f);
      float e = __expf(-t);
      float ge = (im[j] - bback) * e;
      s0 += ge;
      sx = fmaf(Xc, ge, sx);
      sy = fmaf(Yc, ge, sy);
      sxx = fmaf(xc2, ge, sxx);
      syy = fmaf(yc2, ge, syy);
      sxy = fmaf(xy, ge, sxy);
      s7 = fmaf(e, e, s7);
      x += 64;
      if (x >= 96) { x -= 96; y += 3; } else { y += 2; }
    }
    // reduce 7 sums
#pragma unroll
    for (int m = 1; m < 64; m <<= 1) {
      s0 += __shfl_xor(s0, m, 64);  sx += __shfl_xor(sx, m, 64);
      sy += __shfl_xor(sy, m, 64);  sxx += __shfl_xor(sxx, m, 64);
      syy += __shfl_xor(syy, m, 64); sxy += __shfl_xor(sxy, m, 64);
      s7 += __shfl_xor(s7, m, 64);
    }
    if ((tid & 63) == 0) {
      float* p = &rbuf[(tid >> 6) * 7];
      p[0] = s0; p[1] = sx; p[2] = sy; p[3] = sxx; p[4] = syy; p[5] = sxy; p[6] = s7;
    }
    __syncthreads();
    if (tid == 0) {
      for (int w2 = 1; w2 < 4; ++w2) {
        const float* p = &rbuf[w2 * 7];
        s0 += p[0]; sx += p[1]; sy += p[2]; sxx += p[3]; syy += p[4]; sxy += p[5]; s7 += p[6];
      }
      // centered -> raw moments, apply A
      float t2 = Ac * s0;
      float t3 = Ac * fmaf(bmux, s0, sx);
      float t4 = Ac * fmaf(bmuy, s0, sy);
      float t5 = Ac * (sxx + 2.f * bmux * sx + bmux * bmux * s0);
      float t6 = Ac * (syy + 2.f * bmuy * sy + bmuy * bmuy * s0);
      float t1 = Ac * (sxy + bmux * sy + bmuy * sx + bmux * bmuy * s0);
      float t7 = Ac * Ac * s7;
      float flux = t2 / (t7 + 1e-10f);
      float back_n = (total - flux) / 9216.f;
      float t2s = fmaxf(t2, 1e-10f);
      float mux_n = t3 / t2s, muy_n = t4 / t2s;
      float sigxx = t5 / t2s - mux_n * mux_n;
      float sigyy = t6 / t2s - muy_n * muy_n;
      float sigxy = t1 / t2s - (t3 * t4) / (t2s * t2s);
      float ax_n = sqrtf(fminf(fmaxf(sigxx * 2.f, 0.81f), 100.f));
      float ay_n = sqrtf(fminf(fmaxf(sigyy * 2.f, 0.81f), 100.f));
      float axy_n = 2.f * sigxy;
      float den = sigxx + sigyy + 1e-10f;
      float e1 = fminf(fmaxf((sigxx - sigyy) / den, -0.99f), 0.99f);
      float e2 = fminf(fmaxf((2.f * sigxy) / den, -0.99f), 0.99f);
      float dx_v = fabsf(sigxx - psxx);
      float dy_v = fabsf(sigyy - psyy);
      // NaN-safe: reference's jnp.max propagates NaN (=> never converges); encode as +inf
      if (!(dx_v == dx_v)) dx_v = __int_as_float(0x7f800000);
      if (!(dy_v == dy_v)) dy_v = __int_as_float(0x7f800000);
      dxx[n * NPAIR + pair] = dx_v;
      dyy[n * NPAIR + pair] = dy_v;
      e1a[n * NPAIR + pair] = e1;
      e2a[n * NPAIR + pair] = e2;
      bool froz = (ax_n == ax) && (ay_n == ay) && (axy_n == axy) &&
                  (mux_n == mux) && (muy_n == muy) && (back_n == back) &&
                  (dx_v == 0.f) && (dy_v == 0.f);
      psxx = sigxx; psyy = sigyy;
      ax = ax_n; ay = ay_n; axy = axy_n; mux = mux_n; muy = muy_n; back = back_n;
      if (froz) {
        for (int m2 = n + 1; m2 < NITER; ++m2) {
          dxx[m2 * NPAIR + pair] = 0.f;
          dyy[m2 * NPAIR + pair] = 0.f;
          e1a[m2 * NPAIR + pair] = e1;
          e2a[m2 * NPAIR + pair] = e2;
        }
        sfroz = 1;
      } else {
        float rho = fminf(fmaxf(axy / (ax * ay + 1e-10f), -0.99f), 0.99f);
        float arb = fmaxf(2.f * (1.f - rho * rho), 1e-10f);
        float Ac2 = 1.f / (TWO_PI_F * ax * ay * sqrtf(1.f - rho * rho));
        bc[0] = mux; bc[1] = muy; bc[2] = back; bc[3] = Ac2;
        bc[4] = 1.f / (arb * ax * ax);
        bc[5] = 1.f / (arb * ay * ay);
        bc[6] = -2.f * axy / (arb * ax * ax * ay * ay);
      }
    }
    __syncthreads();
    if (sfroz) break;
  }
}

// ---------------- ellipticity: stop-time + loss (kernel B) ----------------

__global__ void ellipB_kernel(const float* __restrict__ dxx, const float* __restrict__ dyy,
                              const float* __restrict__ e1a, const float* __restrict__ e2a,
                              float* __restrict__ out_ellip) {
  __shared__ float rb[8];
  __shared__ int found;
  __shared__ int eidx_sh[2];
  __shared__ float lds[4];
  const int tid = threadIdx.x;

  for (int s = 0; s < 2; ++s) {
    if (tid == 0) { eidx_sh[s] = NITER - 1; found = 0; }
    __syncthreads();
#pragma unroll 1
    for (int n = 0; n < NITER - 1; ++n) {
      int base = n * NPAIR + s * NBATCH;
      float m1 = fmaxf(dxx[base + tid], dxx[base + tid + 256]);
      float m2 = fmaxf(dyy[base + tid], dyy[base + tid + 256]);
#pragma unroll
      for (int m = 1; m < 64; m <<= 1) {
        m1 = fmaxf(m1, __shfl_xor(m1, m, 64));
        m2 = fmaxf(m2, __shfl_xor(m2, m, 64));
      }
      if ((tid & 63) == 0) { rb[(tid >> 6) * 2] = m1; rb[(tid >> 6) * 2 + 1] = m2; }
      __syncthreads();
      if (tid == 0) {
        float M1 = fmaxf(fmaxf(rb[0], rb[2]), fmaxf(rb[4], rb[6]));
        float M2 = fmaxf(fmaxf(rb[1], rb[3]), fmaxf(rb[5], rb[7]));
        if (M1 < 1e-3f && M2 < 1e-3f) { eidx_sh[s] = n; found = 1; }
      }
      __syncthreads();
      if (found) break;
    }
    __syncthreads();
  }

  int i0 = eidx_sh[0], i1 = eidx_sh[1];
  float part = 0.f;
  for (int b = tid; b < NBATCH; b += 256) {
    float e1t = e1a[i0 * NPAIR + b];
    float e2t = e2a[i0 * NPAIR + b];
    float e1p = e1a[i1 * NPAIR + NBATCH + b];
    float e2p = e2a[i1 * NPAIR + NBATCH + b];
    if (!(e1t == e1t)) e1t = 0.f;
    if (!(e2t == e2t)) e2t = 0.f;
    if (!(e1p == e1p)) e1p = 0.f;
    if (!(e2p == e2p)) e2p = 0.f;
    float d1 = e1t - e1p, d2 = e2t - e2p;
    part += d1 * d1 + d2 * d2;
  }
  part = block_reduce_sum(part, lds);
  if (tid == 0) out_ellip[0] = part / (float)NBATCH;
}

// ---------------- final assembly ----------------

__global__ void final_kernel(const double* acc, const float* ellip, float* out) {
  if (threadIdx.x == 0) {
    const double N = 4718592.0;
    float wm = (float)(acc[0] / N);
    float rb = (float)(acc[1] / N);
    out[0] = 100.f * wm + 10.f * rb;
    out[1] = wm;
    out[2] = ellip[0];
    out[3] = rb;
  }
}

// ---------------- launcher ----------------

extern "C" void kernel_launch(void* const* d_in, const int* in_sizes, int n_in,
                              void* d_out, int out_size, void* d_ws, size_t ws_size,
                              hipStream_t stream) {
  const float* blurred = (const float*)d_in[0];
  const float* kernel_img = (const float*)d_in[1];
  const float* wmap = (const float*)d_in[2];
  const float* y_true = (const float*)d_in[3];
  const float* y_pred = (const float*)d_in[4];
  float* out = (float*)d_out;

  // workspace layout
  double* acc = (double*)d_ws;              // acc[0]=wmse sum, acc[1]=reblur sum
  float* wsf = (float*)d_ws;
  float* ellip = wsf + 4;                   // 1 float
  float* vmin = wsf + 8;                    // 512
  float* vmax = vmin + NBATCH;              // 512
  float* totals = vmax + NBATCH;            // 1024
  float* dxx = totals + NPAIR;              // 100*1024
  float* dyy = dxx + NITER * NPAIR;
  float* e1a = dyy + NITER * NPAIR;
  float* e2a = e1a + NITER * NPAIR;

  init_kernel<<<1, 64, 0, stream>>>(acc);
  totals_kernel<<<NPAIR, 256, 0, stream>>>(y_true, y_pred, totals);
  percentile_kernel<<<NBATCH, 256, 0, stream>>>(blurred, vmin, vmax);
  wmse_kernel<<<1024, 256, 0, stream>>>((const float4*)y_true, (const float4*)y_pred,
                                        (const float4*)wmap, acc);
  conv_kernel<<<NBATCH, 256, 0, stream>>>(y_pred, kernel_img, blurred, wmap, vmin, vmax, acc);
  ellipA_kernel<<<NPAIR, 256, 0, stream>>>(y_true, y_pred, totals, dxx, dyy, e1a, e2a);
  ellipB_kernel<<<1, 256, 0, stream>>>(dxx, dyy, e1a, e2a, ellip);
  final_kernel<<<1, 64, 0, stream>>>(acc, ellip, out);
}